// Round 9
// baseline (1002.689 us; speedup 1.0000x reference)
//
#include <hip/hip_runtime.h>
#include <math.h>

#define D_MODEL 1024
#define NH      16
#define DH      64
#define S_LEN   2048
#define BATCH   4

typedef unsigned short u16;
typedef __attribute__((ext_vector_type(8))) short s8v;   // 8 bf16 (4 VGPRs)
typedef __attribute__((ext_vector_type(4))) float f4v;   // 4 f32 acc

#define MFMA(a, b, c) __builtin_amdgcn_mfma_f32_16x16x32_bf16((a), (b), (c), 0, 0, 0)

__device__ inline u16 f2bf(float f) {                    // RNE
  unsigned u = __float_as_uint(f);
  u += 0x7fffu + ((u >> 16) & 1u);
  return (u16)(u >> 16);
}
__device__ inline float bf2f(u16 h) {
  return __uint_as_float(((unsigned)h) << 16);
}
__device__ inline u16 f2bf_trunc(float f) {              // for lo-residuals: trunc is fine (2^-17 rel)
  return (u16)(__float_as_uint(f) >> 16);
}
__device__ inline void split4(const float4 v, short4& h4, short4& l4) {
  u16 hx = f2bf(v.x), hy = f2bf(v.y), hz = f2bf(v.z), hw = f2bf(v.w);
  h4 = make_short4((short)hx, (short)hy, (short)hz, (short)hw);
  l4 = make_short4((short)f2bf_trunc(v.x - bf2f(hx)), (short)f2bf_trunc(v.y - bf2f(hy)),
                   (short)f2bf_trunc(v.z - bf2f(hz)), (short)f2bf_trunc(v.w - bf2f(hw)));
}

// ---------------------------------------------------------------------------
// RoPE table: tab[0:65536) = cos, tab[65536:131072) = sin, idx = s*32 + p
// ---------------------------------------------------------------------------
__global__ void rope_table_kernel(float* __restrict__ tab) {
  int i = blockIdx.x * 256 + threadIdx.x;
  if (i >= S_LEN * 32) return;
  int s = i >> 5;
  int p = i & 31;
  float invf = (float)pow(10000.0, -(double)p / 32.0);
  float ang = (float)s * invf;
  tab[i]         = cosf(ang);
  tab[65536 + i] = sinf(ang);
}

// ---------------------------------------------------------------------------
// Split-bf16 MFMA GEMM:  C[M,N] = A[M,K] * B[N,K]^T  (fp32 in)
// BM=BN=128, BK=32, 256 threads = 4 waves (2x2), 64x64 per wave.
// MODE 0: plain fp32 store to C.
// MODE 1: QKV epilogue -> RoPE; q,k stored as bf16 hi/lo planes [b,h,s,d];
//         v stored fp32 natural [b,h,s,d] (transposed by vtrans_kernel).
// ---------------------------------------------------------------------------
template <int MODE>
__global__ __launch_bounds__(256) void gemm_mfma(
    const float* __restrict__ A, const float* __restrict__ B,
    float* __restrict__ C,
    u16* __restrict__ qh, u16* __restrict__ ql,
    u16* __restrict__ kh, u16* __restrict__ kl,
    float* __restrict__ vw,
    const float* __restrict__ tab,
    int M, int N, int K)
{
  __shared__ short As[2][128][40];   // [hi/lo][row][k], pad 32->40
  __shared__ short Bs[2][128][40];

  const int tid  = threadIdx.x;
  const int lane = tid & 63;
  const int wave = tid >> 6;
  const int wm = wave >> 1, wn = wave & 1;
  const int m0 = blockIdx.y * 128;
  const int n0 = blockIdx.x * 128;

  const int lr = lane & 15;
  const int lk = (lane >> 4) * 8;

  f4v acc[4][4] = {};

  float4 av[4], bv[4];
#pragma unroll
  for (int q = 0; q < 4; ++q) {           // prologue load, k0 = 0
    int f = q * 256 + tid;
    int r = f >> 3, kk = (f & 7) * 4;
    av[q] = *(const float4*)&A[(size_t)(m0 + r) * K + kk];
    bv[q] = *(const float4*)&B[(size_t)(n0 + r) * K + kk];
  }

  for (int k0 = 0; k0 < K; k0 += 32) {
    __syncthreads();
#pragma unroll
    for (int q = 0; q < 4; ++q) {
      int f = q * 256 + tid;
      int r = f >> 3, kk = (f & 7) * 4;
      short4 h4, l4;
      split4(av[q], h4, l4);
      *(short4*)&As[0][r][kk] = h4;  *(short4*)&As[1][r][kk] = l4;
      split4(bv[q], h4, l4);
      *(short4*)&Bs[0][r][kk] = h4;  *(short4*)&Bs[1][r][kk] = l4;
    }
    __syncthreads();

    if (k0 + 32 < K) {                     // prefetch next chunk
#pragma unroll
      for (int q = 0; q < 4; ++q) {
        int f = q * 256 + tid;
        int r = f >> 3, kk = (f & 7) * 4;
        av[q] = *(const float4*)&A[(size_t)(m0 + r) * K + k0 + 32 + kk];
        bv[q] = *(const float4*)&B[(size_t)(n0 + r) * K + k0 + 32 + kk];
      }
    }

    s8v ah[4], al[4], bh[4], bl[4];
#pragma unroll
    for (int x = 0; x < 4; ++x) {
      ah[x] = *(const s8v*)&As[0][wm * 64 + x * 16 + lr][lk];
      al[x] = *(const s8v*)&As[1][wm * 64 + x * 16 + lr][lk];
      bh[x] = *(const s8v*)&Bs[0][wn * 64 + x * 16 + lr][lk];
      bl[x] = *(const s8v*)&Bs[1][wn * 64 + x * 16 + lr][lk];
    }
#pragma unroll
    for (int mf = 0; mf < 4; ++mf)
#pragma unroll
      for (int nf = 0; nf < 4; ++nf) {
        acc[mf][nf] = MFMA(ah[mf], bh[nf], acc[mf][nf]);
        acc[mf][nf] = MFMA(al[mf], bh[nf], acc[mf][nf]);
        acc[mf][nf] = MFMA(ah[mf], bl[nf], acc[mf][nf]);
      }
  }

  // epilogue — D layout: col = lane&15, row = (lane>>4)*4 + i
  if (MODE == 0) {
#pragma unroll
    for (int mf = 0; mf < 4; ++mf)
#pragma unroll
      for (int nf = 0; nf < 4; ++nf) {
        int c = n0 + wn * 64 + nf * 16 + lr;
#pragma unroll
        for (int i = 0; i < 4; ++i) {
          int m = m0 + wm * 64 + mf * 16 + (lane >> 4) * 4 + i;
          C[(size_t)m * N + c] = acc[mf][nf][i];
        }
      }
  } else {
#pragma unroll
    for (int nf = 0; nf < 4; ++nf) {
      int c = n0 + wn * 64 + nf * 16 + lr;     // global output feature
      int t = c >> 10;                          // 0=q 1=k 2=v
      int h = (c & 1023) >> 6;
      int d = c & 63;
#pragma unroll
      for (int mf = 0; mf < 4; ++mf)
#pragma unroll
        for (int i = 0; i < 4; ++i) {
          int m = m0 + wm * 64 + mf * 16 + (lane >> 4) * 4 + i;
          int b = m >> 11, s = m & 2047;
          float v  = acc[mf][nf][i];
          float pv = __shfl_xor(v, 1);          // partner column (c^1), same row
          size_t off = ((size_t)(b * NH + h) * S_LEN + s) * DH + d;
          if (t == 2) {
            vw[off] = v;
          } else {
            int p = d >> 1;
            float co = tab[s * 32 + p], si = tab[65536 + s * 32 + p];
            float res = ((d & 1) == 0) ? (v * co - pv * si)
                                       : (pv * si + v * co);
            u16 hi = f2bf(res);
            u16 lo = f2bf_trunc(res - bf2f(hi));
            ((t == 0) ? qh : kh)[off] = hi;
            ((t == 0) ? ql : kl)[off] = lo;
          }
        }
    }
  }
}

// ---------------------------------------------------------------------------
// V transpose: vw fp32 [bh][s][64] -> vth/vtl bf16 [bh][64][2048]
// ---------------------------------------------------------------------------
__global__ __launch_bounds__(256) void vtrans_kernel(
    const float* __restrict__ vw, u16* __restrict__ vth, u16* __restrict__ vtl)
{
  __shared__ float T[64][65];
  const int tid = threadIdx.x;
  const int st = blockIdx.x, bh = blockIdx.y;
  const int s0 = st * 64;
#pragma unroll
  for (int it = 0; it < 4; ++it) {
    int f = it * 256 + tid;                // 0..1023
    int r = f >> 4, c4 = (f & 15) * 4;
    float4 v = *(const float4*)&vw[((size_t)bh * S_LEN + s0 + r) * DH + c4];
    T[r][c4 + 0] = v.x; T[r][c4 + 1] = v.y; T[r][c4 + 2] = v.z; T[r][c4 + 3] = v.w;
  }
  __syncthreads();
#pragma unroll
  for (int it = 0; it < 16; ++it) {
    int f = it * 256 + tid;                // 0..4095
    int d = f >> 6, sc = f & 63;
    float v = T[sc][d];
    u16 hi = f2bf(v);
    size_t off = ((size_t)bh * DH + d) * S_LEN + s0 + sc;
    vth[off] = hi;
    vtl[off] = f2bf_trunc(v - bf2f(hi));
  }
}

// ---------------------------------------------------------------------------
// Flash attention, split-bf16 MFMA, NO K/V LDS staging (direct L2 fragment
// reads), no __syncthreads (P is wave-private LDS). 256 thr = 4 waves, each
// wave owns a 16-row q stripe; KV tiles of 64.
// ---------------------------------------------------------------------------
__global__ __launch_bounds__(256, 4) void attn2_kernel(
    const u16* __restrict__ qhp, const u16* __restrict__ qlp,
    const u16* __restrict__ khp, const u16* __restrict__ klp,
    const u16* __restrict__ vthp, const u16* __restrict__ vtlp,
    float* __restrict__ ow)
{
  __shared__ u16 Ph[4][16][72];   // wave-private P hi (pad 64->72: 144B rows, 16B-aligned)
  __shared__ u16 Pl[4][16][72];

  const int tid  = threadIdx.x;
  const int lane = tid & 63;
  const int w    = tid >> 6;
  // XCD-chunked swizzle (2048 % 8 == 0 -> bijective) + work-descending qt
  const int bid = blockIdx.x;
  const int swz = (bid & 7) * 256 + (bid >> 3);
  const int bh  = swz >> 5;
  const int qt  = 31 - (swz & 31);
  const int q0  = qt * 64;

  const int lr = lane & 15;
  const int lk = (lane >> 4) * 8;
  const int rg = (lane >> 4) * 4;

  const size_t kvbase = (size_t)bh * S_LEN * DH;     // [bh][s][64] planes
  const size_t vtbase = (size_t)bh * DH * S_LEN;     // [bh][64][2048] planes

  // ---- Q fragments, loaded once, direct from global ----
  const u16* qrow_h = qhp + kvbase + (size_t)(q0 + w * 16 + lr) * DH;
  const u16* qrow_l = qlp + kvbase + (size_t)(q0 + w * 16 + lr) * DH;
  s8v qfh[2], qfl[2];
#pragma unroll
  for (int c = 0; c < 2; ++c) {
    qfh[c] = *(const s8v*)(qrow_h + c * 32 + lk);
    qfl[c] = *(const s8v*)(qrow_l + c * 32 + lk);
  }

  float m_run[4] = {-3.0e38f, -3.0e38f, -3.0e38f, -3.0e38f};
  float l_run[4] = {0.f, 0.f, 0.f, 0.f};
  f4v o[4] = {};

  for (int kt = 0; kt <= qt; ++kt) {
    const int k0 = kt * 64;

    // ---- S = Q K^T : K fragments direct from global (L2) ----
    f4v sf[4] = {};
#pragma unroll
    for (int f = 0; f < 4; ++f) {
      const u16* kr_h = khp + kvbase + (size_t)(k0 + f * 16 + lr) * DH;
      const u16* kr_l = klp + kvbase + (size_t)(k0 + f * 16 + lr) * DH;
#pragma unroll
      for (int c = 0; c < 2; ++c) {
        s8v kbh = *(const s8v*)(kr_h + c * 32 + lk);
        s8v kbl = *(const s8v*)(kr_l + c * 32 + lk);
        sf[f] = MFMA(qfh[c], kbh, sf[f]);
        sf[f] = MFMA(qfl[c], kbh, sf[f]);
        sf[f] = MFMA(qfh[c], kbl, sf[f]);
      }
    }

    // ---- scale + causal mask + online softmax ----
    const bool diag = (kt == qt);
    float p[4][4];
    float sc[4][4];
#pragma unroll
    for (int f = 0; f < 4; ++f)
#pragma unroll
      for (int i = 0; i < 4; ++i) {
        float v = sf[f][i] * 0.125f;
        if (diag) {
          int col = f * 16 + lr;
          int row = w * 16 + rg + i;
          if (col > row) v = -3.0e38f;
        }
        sc[f][i] = v;
      }
#pragma unroll
    for (int i = 0; i < 4; ++i) {
      float mx = fmaxf(fmaxf(sc[0][i], sc[1][i]), fmaxf(sc[2][i], sc[3][i]));
#pragma unroll
      for (int off = 1; off < 16; off <<= 1) mx = fmaxf(mx, __shfl_xor(mx, off));
      float mnew  = fmaxf(m_run[i], mx);
      float alpha = __expf(m_run[i] - mnew);
      float rs = 0.f;
#pragma unroll
      for (int f = 0; f < 4; ++f) { p[f][i] = __expf(sc[f][i] - mnew); rs += p[f][i]; }
#pragma unroll
      for (int off = 1; off < 16; off <<= 1) rs += __shfl_xor(rs, off);
      l_run[i] = l_run[i] * alpha + rs;
      m_run[i] = mnew;
#pragma unroll
      for (int f2 = 0; f2 < 4; ++f2) o[f2][i] *= alpha;
    }

    // ---- write P hi/lo to wave-private LDS (same-wave DS ops are in-order;
    //      compiler tracks the reg deps for the reads below) ----
#pragma unroll
    for (int f = 0; f < 4; ++f)
#pragma unroll
      for (int i = 0; i < 4; ++i) {
        u16 hi = f2bf(p[f][i]);
        Ph[w][rg + i][f * 16 + lr] = hi;
        Pl[w][rg + i][f * 16 + lr] = f2bf_trunc(p[f][i] - bf2f(hi));
      }

    // ---- O += P V : V^T fragments direct from global (L2) ----
#pragma unroll
    for (int c = 0; c < 2; ++c) {
      s8v pah = *(const s8v*)&Ph[w][lr][c * 32 + lk];
      s8v pal = *(const s8v*)&Pl[w][lr][c * 32 + lk];
#pragma unroll
      for (int f2 = 0; f2 < 4; ++f2) {
        const u16* vr_h = vthp + vtbase + (size_t)(f2 * 16 + lr) * S_LEN + k0 + c * 32 + lk;
        const u16* vr_l = vtlp + vtbase + (size_t)(f2 * 16 + lr) * S_LEN + k0 + c * 32 + lk;
        s8v vbh = *(const s8v*)vr_h;
        s8v vbl = *(const s8v*)vr_l;
        o[f2] = MFMA(pah, vbh, o[f2]);
        o[f2] = MFMA(pal, vbh, o[f2]);
        o[f2] = MFMA(pah, vbl, o[f2]);
      }
    }
  }

  // ---- epilogue: divide by l, scatter to [b][s][h*64+d] ----
  const int b = bh >> 4, h = bh & 15;
#pragma unroll
  for (int i = 0; i < 4; ++i) {
    int s = q0 + w * 16 + rg + i;
    float inv = 1.0f / l_run[i];
#pragma unroll
    for (int f2 = 0; f2 < 4; ++f2) {
      int d = f2 * 16 + lr;
      ow[((size_t)(b * S_LEN + s)) * D_MODEL + h * DH + d] = o[f2][i] * inv;
    }
  }
}

// ---------------------------------------------------------------------------
extern "C" void kernel_launch(void* const* d_in, const int* in_sizes, int n_in,
                              void* d_out, int out_size, void* d_ws, size_t ws_size,
                              hipStream_t stream) {
  const float* x     = (const float*)d_in[0];
  const float* w_qkv = (const float*)d_in[1];
  const float* w_out = (const float*)d_in[2];
  float* out = (float*)d_out;

  const size_t NQ = (size_t)BATCH * NH * S_LEN * DH;   // 8388608
  float* ws    = (float*)d_ws;
  float* tab   = ws;                                   // 131072 floats
  float* vw_ow = ws + 131072;                          // fp32 v, later reused as attn out (ow)
  u16*   us    = (u16*)(vw_ow + NQ);
  u16* qh  = us;            u16* ql  = qh + NQ;
  u16* kh  = ql + NQ;       u16* kl  = kh + NQ;
  u16* vth = kl + NQ;       u16* vtl = vth + NQ;
  // total ws: (131072 + NQ)*4 + 6*NQ*2 B ~ 130.5 MB

  const int M = BATCH * S_LEN;   // 8192

  rope_table_kernel<<<(S_LEN * 32 + 255) / 256, 256, 0, stream>>>(tab);

  gemm_mfma<1><<<dim3(3 * D_MODEL / 128, M / 128), 256, 0, stream>>>(
      x, w_qkv, nullptr, qh, ql, kh, kl, vw_ow, tab, M, 3 * D_MODEL, D_MODEL);

  vtrans_kernel<<<dim3(S_LEN / 64, BATCH * NH), 256, 0, stream>>>(vw_ow, vth, vtl);

  attn2_kernel<<<dim3(S_LEN / 64 * BATCH * NH), 256, 0, stream>>>(
      qh, ql, kh, kl, vth, vtl, vw_ow);

  gemm_mfma<0><<<dim3(D_MODEL / 128, M / 128), 256, 0, stream>>>(
      vw_ow, w_out, out, nullptr, nullptr, nullptr, nullptr, nullptr, tab,
      M, D_MODEL, D_MODEL);
}

// Round 13
// 627.334 us; speedup vs baseline: 1.5983x; 1.5983x over previous
//
#include <hip/hip_runtime.h>
#include <math.h>

#define D_MODEL 1024
#define NH      16
#define DH      64
#define S_LEN   2048
#define BATCH   4

typedef unsigned short u16;
typedef __attribute__((ext_vector_type(8))) short s8v;   // 8 bf16 (4 VGPRs)
typedef __attribute__((ext_vector_type(4))) float f4v;   // 4 f32 acc

#define MFMA(a, b, c) __builtin_amdgcn_mfma_f32_16x16x32_bf16((a), (b), (c), 0, 0, 0)

__device__ inline u16 f2bf(float f) {                    // RNE
  unsigned u = __float_as_uint(f);
  u += 0x7fffu + ((u >> 16) & 1u);
  return (u16)(u >> 16);
}
__device__ inline float bf2f(u16 h) {
  return __uint_as_float(((unsigned)h) << 16);
}
__device__ inline u16 f2bf_trunc(float f) {              // lo-residual: trunc ok (2^-17 rel)
  return (u16)(__float_as_uint(f) >> 16);
}
__device__ inline void split4(const float4 v, short4& h4, short4& l4) {
  u16 hx = f2bf(v.x), hy = f2bf(v.y), hz = f2bf(v.z), hw = f2bf(v.w);
  h4 = make_short4((short)hx, (short)hy, (short)hz, (short)hw);
  l4 = make_short4((short)f2bf_trunc(v.x - bf2f(hx)), (short)f2bf_trunc(v.y - bf2f(hy)),
                   (short)f2bf_trunc(v.z - bf2f(hz)), (short)f2bf_trunc(v.w - bf2f(hw)));
}

// ---------------------------------------------------------------------------
// RoPE table: tab[0:65536) = cos, tab[65536:131072) = sin, idx = s*32 + p
// ---------------------------------------------------------------------------
__global__ void rope_table_kernel(float* __restrict__ tab) {
  int i = blockIdx.x * 256 + threadIdx.x;
  if (i >= S_LEN * 32) return;
  int s = i >> 5;
  int p = i & 31;
  float invf = (float)pow(10000.0, -(double)p / 32.0);
  float ang = (float)s * invf;
  tab[i]         = cosf(ang);
  tab[65536 + i] = sinf(ang);
}

// ---------------------------------------------------------------------------
// Split-bf16 MFMA GEMM:  C[M,N] = A[M,K] * B[N,K]^T  (fp32 in)  — unchanged
// ---------------------------------------------------------------------------
template <int MODE>
__global__ __launch_bounds__(256) void gemm_mfma(
    const float* __restrict__ A, const float* __restrict__ B,
    float* __restrict__ C,
    u16* __restrict__ qh, u16* __restrict__ ql,
    u16* __restrict__ kh, u16* __restrict__ kl,
    float* __restrict__ vw,
    const float* __restrict__ tab,
    int M, int N, int K)
{
  __shared__ short As[2][128][40];
  __shared__ short Bs[2][128][40];

  const int tid  = threadIdx.x;
  const int lane = tid & 63;
  const int wave = tid >> 6;
  const int wm = wave >> 1, wn = wave & 1;
  const int m0 = blockIdx.y * 128;
  const int n0 = blockIdx.x * 128;

  const int lr = lane & 15;
  const int lk = (lane >> 4) * 8;

  f4v acc[4][4] = {};

  float4 av[4], bv[4];
#pragma unroll
  for (int q = 0; q < 4; ++q) {
    int f = q * 256 + tid;
    int r = f >> 3, kk = (f & 7) * 4;
    av[q] = *(const float4*)&A[(size_t)(m0 + r) * K + kk];
    bv[q] = *(const float4*)&B[(size_t)(n0 + r) * K + kk];
  }

  for (int k0 = 0; k0 < K; k0 += 32) {
    __syncthreads();
#pragma unroll
    for (int q = 0; q < 4; ++q) {
      int f = q * 256 + tid;
      int r = f >> 3, kk = (f & 7) * 4;
      short4 h4, l4;
      split4(av[q], h4, l4);
      *(short4*)&As[0][r][kk] = h4;  *(short4*)&As[1][r][kk] = l4;
      split4(bv[q], h4, l4);
      *(short4*)&Bs[0][r][kk] = h4;  *(short4*)&Bs[1][r][kk] = l4;
    }
    __syncthreads();

    if (k0 + 32 < K) {
#pragma unroll
      for (int q = 0; q < 4; ++q) {
        int f = q * 256 + tid;
        int r = f >> 3, kk = (f & 7) * 4;
        av[q] = *(const float4*)&A[(size_t)(m0 + r) * K + k0 + 32 + kk];
        bv[q] = *(const float4*)&B[(size_t)(n0 + r) * K + k0 + 32 + kk];
      }
    }

    s8v ah[4], al[4], bh[4], bl[4];
#pragma unroll
    for (int x = 0; x < 4; ++x) {
      ah[x] = *(const s8v*)&As[0][wm * 64 + x * 16 + lr][lk];
      al[x] = *(const s8v*)&As[1][wm * 64 + x * 16 + lr][lk];
      bh[x] = *(const s8v*)&Bs[0][wn * 64 + x * 16 + lr][lk];
      bl[x] = *(const s8v*)&Bs[1][wn * 64 + x * 16 + lr][lk];
    }
#pragma unroll
    for (int mf = 0; mf < 4; ++mf)
#pragma unroll
      for (int nf = 0; nf < 4; ++nf) {
        acc[mf][nf] = MFMA(ah[mf], bh[nf], acc[mf][nf]);
        acc[mf][nf] = MFMA(al[mf], bh[nf], acc[mf][nf]);
        acc[mf][nf] = MFMA(ah[mf], bl[nf], acc[mf][nf]);
      }
  }

  if (MODE == 0) {
#pragma unroll
    for (int mf = 0; mf < 4; ++mf)
#pragma unroll
      for (int nf = 0; nf < 4; ++nf) {
        int c = n0 + wn * 64 + nf * 16 + lr;
#pragma unroll
        for (int i = 0; i < 4; ++i) {
          int m = m0 + wm * 64 + mf * 16 + (lane >> 4) * 4 + i;
          C[(size_t)m * N + c] = acc[mf][nf][i];
        }
      }
  } else {
#pragma unroll
    for (int nf = 0; nf < 4; ++nf) {
      int c = n0 + wn * 64 + nf * 16 + lr;
      int t = c >> 10;
      int h = (c & 1023) >> 6;
      int d = c & 63;
#pragma unroll
      for (int mf = 0; mf < 4; ++mf)
#pragma unroll
        for (int i = 0; i < 4; ++i) {
          int m = m0 + wm * 64 + mf * 16 + (lane >> 4) * 4 + i;
          int b = m >> 11, s = m & 2047;
          float v  = acc[mf][nf][i];
          float pv = __shfl_xor(v, 1);
          size_t off = ((size_t)(b * NH + h) * S_LEN + s) * DH + d;
          if (t == 2) {
            vw[off] = v;
          } else {
            int p = d >> 1;
            float co = tab[s * 32 + p], si = tab[65536 + s * 32 + p];
            float res = ((d & 1) == 0) ? (v * co - pv * si)
                                       : (pv * si + v * co);
            u16 hi = f2bf(res);
            u16 lo = f2bf_trunc(res - bf2f(hi));
            ((t == 0) ? qh : kh)[off] = hi;
            ((t == 0) ? ql : kl)[off] = lo;
          }
        }
    }
  }
}

// ---------------------------------------------------------------------------
// V transpose: vw fp32 [bh][s][64] -> vth/vtl bf16 [bh][64][2048]  — unchanged
// ---------------------------------------------------------------------------
__global__ __launch_bounds__(256) void vtrans_kernel(
    const float* __restrict__ vw, u16* __restrict__ vth, u16* __restrict__ vtl)
{
  __shared__ float T[64][65];
  const int tid = threadIdx.x;
  const int st = blockIdx.x, bh = blockIdx.y;
  const int s0 = st * 64;
#pragma unroll
  for (int it = 0; it < 4; ++it) {
    int f = it * 256 + tid;
    int r = f >> 4, c4 = (f & 15) * 4;
    float4 v = *(const float4*)&vw[((size_t)bh * S_LEN + s0 + r) * DH + c4];
    T[r][c4 + 0] = v.x; T[r][c4 + 1] = v.y; T[r][c4 + 2] = v.z; T[r][c4 + 3] = v.w;
  }
  __syncthreads();
#pragma unroll
  for (int it = 0; it < 16; ++it) {
    int f = it * 256 + tid;
    int d = f >> 6, sc = f & 63;
    float v = T[sc][d];
    u16 hi = f2bf(v);
    size_t off = ((size_t)bh * DH + d) * S_LEN + s0 + sc;
    vth[off] = hi;
    vtl[off] = f2bf_trunc(v - bf2f(hi));
  }
}

// ---------------------------------------------------------------------------
// Flash attention v3b: block-shared LDS staging of pre-split K / V^T planes,
// T14 async prefetch. FIXED staging coverage: 4 threads/row x 32B = full
// 128B row per plane (round 10 staged only half the tile -> NaN).
// ---------------------------------------------------------------------------
__global__ __launch_bounds__(256) void attn3_kernel(
    const u16* __restrict__ qhp, const u16* __restrict__ qlp,
    const u16* __restrict__ khp, const u16* __restrict__ klp,
    const u16* __restrict__ vthp, const u16* __restrict__ vtlp,
    float* __restrict__ ow)
{
  __shared__ u16 Kh[64][72], Kl[64][72];        // K tile  [s][d], pad 64->72
  __shared__ u16 Vh[64][72], Vl[64][72];        // V^T tile [d][s]
  __shared__ u16 Ph[4][16][72], Pl[4][16][72];  // wave-private P

  const int tid  = threadIdx.x;
  const int lane = tid & 63;
  const int w    = tid >> 6;
  // XCD-chunked swizzle + work-descending qt
  const int bid = blockIdx.x;
  const int swz = (bid & 7) * 256 + (bid >> 3);
  const int bh  = swz >> 5;
  const int qt  = 31 - (swz & 31);
  const int q0  = qt * 64;

  const int lr = lane & 15;
  const int lk = (lane >> 4) * 8;
  const int rg = (lane >> 4) * 4;

  const size_t kvbase = (size_t)bh * S_LEN * DH;   // [bh][s][64]
  const size_t vtbase = (size_t)bh * DH * S_LEN;   // [bh][64][2048]

  // staging: thread t -> row sr = t>>2, 32B chunk sc0 = (t&3)*16  (full 64-elem row)
  const int sr  = tid >> 2;
  const int sc0 = (tid & 3) * 16;

  // ---- Q fragments (loaded once, direct) ----
  const u16* qrow_h = qhp + kvbase + (size_t)(q0 + w * 16 + lr) * DH;
  const u16* qrow_l = qlp + kvbase + (size_t)(q0 + w * 16 + lr) * DH;
  s8v qfh[2], qfl[2];
#pragma unroll
  for (int c = 0; c < 2; ++c) {
    qfh[c] = *(const s8v*)(qrow_h + c * 32 + lk);
    qfl[c] = *(const s8v*)(qrow_l + c * 32 + lk);
  }

  float m_run[4] = {-3.0e38f, -3.0e38f, -3.0e38f, -3.0e38f};
  float l_run[4] = {0.f, 0.f, 0.f, 0.f};
  f4v o[4] = {};

  // prologue: load tile 0 into staging regs (2 x s8v per plane = 32B)
  s8v rkh[2], rkl[2], rvh[2], rvl[2];
  {
    const size_t koff = kvbase + (size_t)sr * DH + sc0;          // k0 = 0
    const size_t voff = vtbase + (size_t)sr * S_LEN + 0 + sc0;
    rkh[0] = *(const s8v*)(khp + koff);   rkh[1] = *(const s8v*)(khp + koff + 8);
    rkl[0] = *(const s8v*)(klp + koff);   rkl[1] = *(const s8v*)(klp + koff + 8);
    rvh[0] = *(const s8v*)(vthp + voff);  rvh[1] = *(const s8v*)(vthp + voff + 8);
    rvl[0] = *(const s8v*)(vtlp + voff);  rvl[1] = *(const s8v*)(vtlp + voff + 8);
  }

  for (int kt = 0; kt <= qt; ++kt) {
    __syncthreads();                      // prev tile fully consumed
    *(s8v*)&Kh[sr][sc0] = rkh[0];  *(s8v*)&Kh[sr][sc0 + 8] = rkh[1];
    *(s8v*)&Kl[sr][sc0] = rkl[0];  *(s8v*)&Kl[sr][sc0 + 8] = rkl[1];
    *(s8v*)&Vh[sr][sc0] = rvh[0];  *(s8v*)&Vh[sr][sc0 + 8] = rvh[1];
    *(s8v*)&Vl[sr][sc0] = rvl[0];  *(s8v*)&Vl[sr][sc0 + 8] = rvl[1];
    __syncthreads();                      // tile staged

    if (kt < qt) {                        // prefetch next tile (lands under compute)
      const int kn = (kt + 1) * 64;
      const size_t koff = kvbase + (size_t)(kn + sr) * DH + sc0;
      const size_t voff = vtbase + (size_t)sr * S_LEN + kn + sc0;
      rkh[0] = *(const s8v*)(khp + koff);   rkh[1] = *(const s8v*)(khp + koff + 8);
      rkl[0] = *(const s8v*)(klp + koff);   rkl[1] = *(const s8v*)(klp + koff + 8);
      rvh[0] = *(const s8v*)(vthp + voff);  rvh[1] = *(const s8v*)(vthp + voff + 8);
      rvl[0] = *(const s8v*)(vtlp + voff);  rvl[1] = *(const s8v*)(vtlp + voff + 8);
    }

    // ---- S = Q K^T from LDS ----
    f4v sf[4] = {};
#pragma unroll
    for (int f = 0; f < 4; ++f)
#pragma unroll
      for (int c = 0; c < 2; ++c) {
        s8v kbh = *(const s8v*)&Kh[f * 16 + lr][c * 32 + lk];
        s8v kbl = *(const s8v*)&Kl[f * 16 + lr][c * 32 + lk];
        sf[f] = MFMA(qfh[c], kbh, sf[f]);
        sf[f] = MFMA(qfl[c], kbh, sf[f]);
        sf[f] = MFMA(qfh[c], kbl, sf[f]);
      }

    // ---- scale + causal mask + online softmax ----
    const bool diag = (kt == qt);
    float p[4][4];
    float sc[4][4];
#pragma unroll
    for (int f = 0; f < 4; ++f)
#pragma unroll
      for (int i = 0; i < 4; ++i) {
        float v = sf[f][i] * 0.125f;
        if (diag) {
          int col = f * 16 + lr;
          int row = w * 16 + rg + i;
          if (col > row) v = -3.0e38f;
        }
        sc[f][i] = v;
      }
#pragma unroll
    for (int i = 0; i < 4; ++i) {
      float mx = fmaxf(fmaxf(sc[0][i], sc[1][i]), fmaxf(sc[2][i], sc[3][i]));
#pragma unroll
      for (int off = 1; off < 16; off <<= 1) mx = fmaxf(mx, __shfl_xor(mx, off));
      float mnew  = fmaxf(m_run[i], mx);
      float alpha = __expf(m_run[i] - mnew);
      float rs = 0.f;
#pragma unroll
      for (int f = 0; f < 4; ++f) { p[f][i] = __expf(sc[f][i] - mnew); rs += p[f][i]; }
#pragma unroll
      for (int off = 1; off < 16; off <<= 1) rs += __shfl_xor(rs, off);
      l_run[i] = l_run[i] * alpha + rs;
      m_run[i] = mnew;
#pragma unroll
      for (int f2 = 0; f2 < 4; ++f2) o[f2][i] *= alpha;
    }

    // ---- P hi/lo to wave-private LDS ----
#pragma unroll
    for (int f = 0; f < 4; ++f)
#pragma unroll
      for (int i = 0; i < 4; ++i) {
        u16 hi = f2bf(p[f][i]);
        Ph[w][rg + i][f * 16 + lr] = hi;
        Pl[w][rg + i][f * 16 + lr] = f2bf_trunc(p[f][i] - bf2f(hi));
      }

    // ---- O += P V from LDS ----
#pragma unroll
    for (int c = 0; c < 2; ++c) {
      s8v pah = *(const s8v*)&Ph[w][lr][c * 32 + lk];
      s8v pal = *(const s8v*)&Pl[w][lr][c * 32 + lk];
#pragma unroll
      for (int f2 = 0; f2 < 4; ++f2) {
        s8v vbh = *(const s8v*)&Vh[f2 * 16 + lr][c * 32 + lk];
        s8v vbl = *(const s8v*)&Vl[f2 * 16 + lr][c * 32 + lk];
        o[f2] = MFMA(pah, vbh, o[f2]);
        o[f2] = MFMA(pal, vbh, o[f2]);
        o[f2] = MFMA(pah, vbl, o[f2]);
      }
    }
  }

  // ---- epilogue ----
  const int b = bh >> 4, h = bh & 15;
#pragma unroll
  for (int i = 0; i < 4; ++i) {
    int s = q0 + w * 16 + rg + i;
    float inv = 1.0f / l_run[i];
#pragma unroll
    for (int f2 = 0; f2 < 4; ++f2) {
      int d = f2 * 16 + lr;
      ow[((size_t)(b * S_LEN + s)) * D_MODEL + h * DH + d] = o[f2][i] * inv;
    }
  }
}

// ---------------------------------------------------------------------------
extern "C" void kernel_launch(void* const* d_in, const int* in_sizes, int n_in,
                              void* d_out, int out_size, void* d_ws, size_t ws_size,
                              hipStream_t stream) {
  const float* x     = (const float*)d_in[0];
  const float* w_qkv = (const float*)d_in[1];
  const float* w_out = (const float*)d_in[2];
  float* out = (float*)d_out;

  const size_t NQ = (size_t)BATCH * NH * S_LEN * DH;   // 8388608
  float* ws    = (float*)d_ws;
  float* tab   = ws;                                   // 131072 floats
  float* vw_ow = ws + 131072;                          // fp32 v, reused as attn out
  u16*   us    = (u16*)(vw_ow + NQ);
  u16* qh  = us;            u16* ql  = qh + NQ;
  u16* kh  = ql + NQ;       u16* kl  = kh + NQ;
  u16* vth = kl + NQ;       u16* vtl = vth + NQ;

  const int M = BATCH * S_LEN;   // 8192

  rope_table_kernel<<<(S_LEN * 32 + 255) / 256, 256, 0, stream>>>(tab);

  gemm_mfma<1><<<dim3(3 * D_MODEL / 128, M / 128), 256, 0, stream>>>(
      x, w_qkv, nullptr, qh, ql, kh, kl, vw_ow, tab, M, 3 * D_MODEL, D_MODEL);

  vtrans_kernel<<<dim3(S_LEN / 64, BATCH * NH), 256, 0, stream>>>(vw_ow, vth, vtl);

  attn3_kernel<<<dim3(S_LEN / 64 * BATCH * NH), 256, 0, stream>>>(
      qh, ql, kh, kl, vth, vtl, vw_ow);

  gemm_mfma<0><<<dim3(D_MODEL / 128, M / 128), 256, 0, stream>>>(
      vw_ow, w_out, out, nullptr, nullptr, nullptr, nullptr, nullptr, tab,
      M, D_MODEL, D_MODEL);
}

// Round 15
// 548.568 us; speedup vs baseline: 1.8278x; 1.1436x over previous
//
#include <hip/hip_runtime.h>
#include <math.h>

#define D_MODEL 1024
#define NH      16
#define DH      64
#define S_LEN   2048
#define BATCH   4

typedef unsigned short u16;
typedef __attribute__((ext_vector_type(8))) short s8v;   // 8 bf16 (4 VGPRs)
typedef __attribute__((ext_vector_type(4))) float f4v;   // 4 f32 acc

#define MFMA(a, b, c) __builtin_amdgcn_mfma_f32_16x16x32_bf16((a), (b), (c), 0, 0, 0)

__device__ inline u16 f2bf(float f) {                    // RNE
  unsigned u = __float_as_uint(f);
  u += 0x7fffu + ((u >> 16) & 1u);
  return (u16)(u >> 16);
}
__device__ inline float bf2f(u16 h) {
  return __uint_as_float(((unsigned)h) << 16);
}
__device__ inline u16 f2bf_trunc(float f) {              // lo-residual: trunc ok
  return (u16)(__float_as_uint(f) >> 16);
}
__device__ inline void split4(const float4 v, short4& h4, short4& l4) {
  u16 hx = f2bf(v.x), hy = f2bf(v.y), hz = f2bf(v.z), hw = f2bf(v.w);
  h4 = make_short4((short)hx, (short)hy, (short)hz, (short)hw);
  l4 = make_short4((short)f2bf_trunc(v.x - bf2f(hx)), (short)f2bf_trunc(v.y - bf2f(hy)),
                   (short)f2bf_trunc(v.z - bf2f(hz)), (short)f2bf_trunc(v.w - bf2f(hw)));
}

// ---------------------------------------------------------------------------
// RoPE table: tab[0:65536) = cos, tab[65536:131072) = sin, idx = s*32 + p
// ---------------------------------------------------------------------------
__global__ void rope_table_kernel(float* __restrict__ tab) {
  int i = blockIdx.x * 256 + threadIdx.x;
  if (i >= S_LEN * 32) return;
  int s = i >> 5;
  int p = i & 31;
  float invf = (float)pow(10000.0, -(double)p / 32.0);
  float ang = (float)s * invf;
  tab[i]         = cosf(ang);
  tab[65536 + i] = sinf(ang);
}

// ---------------------------------------------------------------------------
// fp32 -> bf16 hi/lo plane split (bandwidth-bound, one pass)
// ---------------------------------------------------------------------------
__global__ __launch_bounds__(256) void split_kernel(
    const float* __restrict__ src, u16* __restrict__ dh, u16* __restrict__ dl, int n4) {
  int i = blockIdx.x * 256 + threadIdx.x;
  if (i >= n4) return;
  float4 v = reinterpret_cast<const float4*>(src)[i];
  short4 h4, l4;
  split4(v, h4, l4);
  reinterpret_cast<short4*>(dh)[i] = h4;
  reinterpret_cast<short4*>(dl)[i] = l4;
}

// ---------------------------------------------------------------------------
// Split-bf16 MFMA GEMM v2: A,B given as PRE-SPLIT bf16 hi/lo planes [.][K].
// C = A*B^T in fp32-equivalent (3 MFMAs). Staging = pure copy, zero VALU.
// BM=BN=128, BK=32, 256 thr = 4 waves (2x2), 64x64/wave.
// MODE 0: fp32 store to C.   MODE 1: RoPE epilogue -> q/k planes + v fp32.
// ---------------------------------------------------------------------------
template <int MODE>
__global__ __launch_bounds__(256) void gemm2(
    const u16* __restrict__ Ah, const u16* __restrict__ Al,
    const u16* __restrict__ Bh, const u16* __restrict__ Bl,
    float* __restrict__ C,
    u16* __restrict__ qh, u16* __restrict__ ql,
    u16* __restrict__ kh, u16* __restrict__ kl,
    float* __restrict__ vw,
    const float* __restrict__ tab,
    int M, int N, int K)
{
  __shared__ u16 As[2][128][40];   // [hi/lo][row][k], pad 32->40
  __shared__ u16 Bs[2][128][40];

  const int tid  = threadIdx.x;
  const int lane = tid & 63;
  const int wave = tid >> 6;
  const int wm = wave >> 1, wn = wave & 1;
  const int m0 = blockIdx.y * 128;
  const int n0 = blockIdx.x * 128;

  const int lr = lane & 15;
  const int lk = (lane >> 4) * 8;

  // staging: thread -> row tid>>1 (0..127), 16-elem chunk (tid&1)*16
  const int srow = tid >> 1;
  const int skc  = (tid & 1) * 16;

  f4v acc[4][4] = {};

  s8v ra[2][2], rb[2][2];                 // [plane][half]
  {
    const size_t ab = (size_t)(m0 + srow) * K + skc;
    const size_t bb = (size_t)(n0 + srow) * K + skc;
    ra[0][0] = *(const s8v*)(Ah + ab);  ra[0][1] = *(const s8v*)(Ah + ab + 8);
    ra[1][0] = *(const s8v*)(Al + ab);  ra[1][1] = *(const s8v*)(Al + ab + 8);
    rb[0][0] = *(const s8v*)(Bh + bb);  rb[0][1] = *(const s8v*)(Bh + bb + 8);
    rb[1][0] = *(const s8v*)(Bl + bb);  rb[1][1] = *(const s8v*)(Bl + bb + 8);
  }

  for (int k0 = 0; k0 < K; k0 += 32) {
    __syncthreads();                      // prev compute done reading LDS
    *(s8v*)&As[0][srow][skc] = ra[0][0];  *(s8v*)&As[0][srow][skc + 8] = ra[0][1];
    *(s8v*)&As[1][srow][skc] = ra[1][0];  *(s8v*)&As[1][srow][skc + 8] = ra[1][1];
    *(s8v*)&Bs[0][srow][skc] = rb[0][0];  *(s8v*)&Bs[0][srow][skc + 8] = rb[0][1];
    *(s8v*)&Bs[1][srow][skc] = rb[1][0];  *(s8v*)&Bs[1][srow][skc + 8] = rb[1][1];
    __syncthreads();                      // tile staged

    if (k0 + 32 < K) {                    // prefetch next chunk under MFMA
      const size_t ab = (size_t)(m0 + srow) * K + k0 + 32 + skc;
      const size_t bb = (size_t)(n0 + srow) * K + k0 + 32 + skc;
      ra[0][0] = *(const s8v*)(Ah + ab);  ra[0][1] = *(const s8v*)(Ah + ab + 8);
      ra[1][0] = *(const s8v*)(Al + ab);  ra[1][1] = *(const s8v*)(Al + ab + 8);
      rb[0][0] = *(const s8v*)(Bh + bb);  rb[0][1] = *(const s8v*)(Bh + bb + 8);
      rb[1][0] = *(const s8v*)(Bl + bb);  rb[1][1] = *(const s8v*)(Bl + bb + 8);
    }

    s8v ah[4], al[4], bh[4], bl[4];
#pragma unroll
    for (int x = 0; x < 4; ++x) {
      ah[x] = *(const s8v*)&As[0][wm * 64 + x * 16 + lr][lk];
      al[x] = *(const s8v*)&As[1][wm * 64 + x * 16 + lr][lk];
      bh[x] = *(const s8v*)&Bs[0][wn * 64 + x * 16 + lr][lk];
      bl[x] = *(const s8v*)&Bs[1][wn * 64 + x * 16 + lr][lk];
    }
#pragma unroll
    for (int mf = 0; mf < 4; ++mf)
#pragma unroll
      for (int nf = 0; nf < 4; ++nf) {
        acc[mf][nf] = MFMA(ah[mf], bh[nf], acc[mf][nf]);
        acc[mf][nf] = MFMA(al[mf], bh[nf], acc[mf][nf]);
        acc[mf][nf] = MFMA(ah[mf], bl[nf], acc[mf][nf]);
      }
  }

  // epilogue — D layout: col = lane&15, row = (lane>>4)*4 + i
  if (MODE == 0) {
#pragma unroll
    for (int mf = 0; mf < 4; ++mf)
#pragma unroll
      for (int nf = 0; nf < 4; ++nf) {
        int c = n0 + wn * 64 + nf * 16 + lr;
#pragma unroll
        for (int i = 0; i < 4; ++i) {
          int m = m0 + wm * 64 + mf * 16 + (lane >> 4) * 4 + i;
          C[(size_t)m * N + c] = acc[mf][nf][i];
        }
      }
  } else {
#pragma unroll
    for (int nf = 0; nf < 4; ++nf) {
      int c = n0 + wn * 64 + nf * 16 + lr;
      int t = c >> 10;                    // 0=q 1=k 2=v
      int h = (c & 1023) >> 6;
      int d = c & 63;
#pragma unroll
      for (int mf = 0; mf < 4; ++mf)
#pragma unroll
        for (int i = 0; i < 4; ++i) {
          int m = m0 + wm * 64 + mf * 16 + (lane >> 4) * 4 + i;
          int b = m >> 11, s = m & 2047;
          float v  = acc[mf][nf][i];
          float pv = __shfl_xor(v, 1);    // partner column (c^1), same row
          size_t off = ((size_t)(b * NH + h) * S_LEN + s) * DH + d;
          if (t == 2) {
            vw[off] = v;
          } else {
            int p = d >> 1;
            float co = tab[s * 32 + p], si = tab[65536 + s * 32 + p];
            float res = ((d & 1) == 0) ? (v * co - pv * si)
                                       : (pv * si + v * co);
            u16 hi = f2bf(res);
            u16 lo = f2bf_trunc(res - bf2f(hi));
            ((t == 0) ? qh : kh)[off] = hi;
            ((t == 0) ? ql : kl)[off] = lo;
          }
        }
    }
  }
}

// ---------------------------------------------------------------------------
// V transpose: vw fp32 [bh][s][64] -> vth bf16 [bh][64][2048] (hi only;
// PV runs pure bf16)
// ---------------------------------------------------------------------------
__global__ __launch_bounds__(256) void vtrans_kernel(
    const float* __restrict__ vw, u16* __restrict__ vth)
{
  __shared__ float T[64][65];
  const int tid = threadIdx.x;
  const int st = blockIdx.x, bh = blockIdx.y;
  const int s0 = st * 64;
#pragma unroll
  for (int it = 0; it < 4; ++it) {
    int f = it * 256 + tid;
    int r = f >> 4, c4 = (f & 15) * 4;
    float4 v = *(const float4*)&vw[((size_t)bh * S_LEN + s0 + r) * DH + c4];
    T[r][c4 + 0] = v.x; T[r][c4 + 1] = v.y; T[r][c4 + 2] = v.z; T[r][c4 + 3] = v.w;
  }
  __syncthreads();
#pragma unroll
  for (int it = 0; it < 16; ++it) {
    int f = it * 256 + tid;
    int d = f >> 6, sc = f & 63;
    vth[((size_t)bh * DH + d) * S_LEN + s0 + sc] = f2bf(T[sc][d]);
  }
}

// ---------------------------------------------------------------------------
// Flash attention v4: r13's validated structure, PV in pure bf16 (1 MFMA),
// no Vl/Pl. LDS 37 KiB -> 4 blocks/CU. Output written as bf16 hi/lo planes
// (feeds pure-copy out-proj GEMM).
// ---------------------------------------------------------------------------
__global__ __launch_bounds__(256) void attn4_kernel(
    const u16* __restrict__ qhp, const u16* __restrict__ qlp,
    const u16* __restrict__ khp, const u16* __restrict__ klp,
    const u16* __restrict__ vthp,
    u16* __restrict__ ohp, u16* __restrict__ olp)
{
  __shared__ u16 Kh[64][72], Kl[64][72];   // K tile [s][d], pad 64->72
  __shared__ u16 Vh[64][72];               // V^T tile [d][s]
  __shared__ u16 Ph[4][16][72];            // wave-private P (bf16)

  const int tid  = threadIdx.x;
  const int lane = tid & 63;
  const int w    = tid >> 6;
  const int bid = blockIdx.x;
  const int swz = (bid & 7) * 256 + (bid >> 3);  // XCD-chunked, bijective
  const int bh  = swz >> 5;
  const int qt  = 31 - (swz & 31);               // work-descending
  const int q0  = qt * 64;

  const int lr = lane & 15;
  const int lk = (lane >> 4) * 8;
  const int rg = (lane >> 4) * 4;

  const size_t kvbase = (size_t)bh * S_LEN * DH;   // [bh][s][64]
  const size_t vtbase = (size_t)bh * DH * S_LEN;   // [bh][64][2048]

  // staging: thread t -> row t>>2, 32B chunk (t&3)*16 (full 64-elem rows)
  const int sr  = tid >> 2;
  const int sc0 = (tid & 3) * 16;

  // ---- Q fragments (loaded once, direct) ----
  const u16* qrow_h = qhp + kvbase + (size_t)(q0 + w * 16 + lr) * DH;
  const u16* qrow_l = qlp + kvbase + (size_t)(q0 + w * 16 + lr) * DH;
  s8v qfh[2], qfl[2];
#pragma unroll
  for (int c = 0; c < 2; ++c) {
    qfh[c] = *(const s8v*)(qrow_h + c * 32 + lk);
    qfl[c] = *(const s8v*)(qrow_l + c * 32 + lk);
  }

  float m_run[4] = {-3.0e38f, -3.0e38f, -3.0e38f, -3.0e38f};
  float l_run[4] = {0.f, 0.f, 0.f, 0.f};
  f4v o[4] = {};

  s8v rkh[2], rkl[2], rvh[2];
  {
    const size_t koff = kvbase + (size_t)sr * DH + sc0;
    const size_t voff = vtbase + (size_t)sr * S_LEN + sc0;
    rkh[0] = *(const s8v*)(khp + koff);   rkh[1] = *(const s8v*)(khp + koff + 8);
    rkl[0] = *(const s8v*)(klp + koff);   rkl[1] = *(const s8v*)(klp + koff + 8);
    rvh[0] = *(const s8v*)(vthp + voff);  rvh[1] = *(const s8v*)(vthp + voff + 8);
  }

  for (int kt = 0; kt <= qt; ++kt) {
    __syncthreads();                      // prev tile fully consumed
    *(s8v*)&Kh[sr][sc0] = rkh[0];  *(s8v*)&Kh[sr][sc0 + 8] = rkh[1];
    *(s8v*)&Kl[sr][sc0] = rkl[0];  *(s8v*)&Kl[sr][sc0 + 8] = rkl[1];
    *(s8v*)&Vh[sr][sc0] = rvh[0];  *(s8v*)&Vh[sr][sc0 + 8] = rvh[1];
    __syncthreads();                      // tile staged

    if (kt < qt) {                        // prefetch next tile under compute
      const int kn = (kt + 1) * 64;
      const size_t koff = kvbase + (size_t)(kn + sr) * DH + sc0;
      const size_t voff = vtbase + (size_t)sr * S_LEN + kn + sc0;
      rkh[0] = *(const s8v*)(khp + koff);   rkh[1] = *(const s8v*)(khp + koff + 8);
      rkl[0] = *(const s8v*)(klp + koff);   rkl[1] = *(const s8v*)(klp + koff + 8);
      rvh[0] = *(const s8v*)(vthp + voff);  rvh[1] = *(const s8v*)(vthp + voff + 8);
    }

    // ---- S = Q K^T (3-MFMA split: exp amplifies S errors, keep precise) ----
    f4v sf[4] = {};
#pragma unroll
    for (int f = 0; f < 4; ++f)
#pragma unroll
      for (int c = 0; c < 2; ++c) {
        s8v kbh = *(const s8v*)&Kh[f * 16 + lr][c * 32 + lk];
        s8v kbl = *(const s8v*)&Kl[f * 16 + lr][c * 32 + lk];
        sf[f] = MFMA(qfh[c], kbh, sf[f]);
        sf[f] = MFMA(qfl[c], kbh, sf[f]);
        sf[f] = MFMA(qfh[c], kbl, sf[f]);
      }

    // ---- scale + causal mask + online softmax ----
    const bool diag = (kt == qt);
    float p[4][4];
    float sc[4][4];
#pragma unroll
    for (int f = 0; f < 4; ++f)
#pragma unroll
      for (int i = 0; i < 4; ++i) {
        float v = sf[f][i] * 0.125f;
        if (diag) {
          int col = f * 16 + lr;
          int row = w * 16 + rg + i;
          if (col > row) v = -3.0e38f;
        }
        sc[f][i] = v;
      }
#pragma unroll
    for (int i = 0; i < 4; ++i) {
      float mx = fmaxf(fmaxf(sc[0][i], sc[1][i]), fmaxf(sc[2][i], sc[3][i]));
#pragma unroll
      for (int off = 1; off < 16; off <<= 1) mx = fmaxf(mx, __shfl_xor(mx, off));
      float mnew  = fmaxf(m_run[i], mx);
      float alpha = __expf(m_run[i] - mnew);
      float rs = 0.f;
#pragma unroll
      for (int f = 0; f < 4; ++f) { p[f][i] = __expf(sc[f][i] - mnew); rs += p[f][i]; }
#pragma unroll
      for (int off = 1; off < 16; off <<= 1) rs += __shfl_xor(rs, off);
      l_run[i] = l_run[i] * alpha + rs;
      m_run[i] = mnew;
#pragma unroll
      for (int f2 = 0; f2 < 4; ++f2) o[f2][i] *= alpha;
    }

    // ---- P (bf16 only) to wave-private LDS ----
#pragma unroll
    for (int f = 0; f < 4; ++f)
#pragma unroll
      for (int i = 0; i < 4; ++i)
        Ph[w][rg + i][f * 16 + lr] = f2bf(p[f][i]);

    // ---- O += P V, pure bf16 (P in [0,1], V bf16: err ~2^-9, not amplified) ----
#pragma unroll
    for (int c = 0; c < 2; ++c) {
      s8v pah = *(const s8v*)&Ph[w][lr][c * 32 + lk];
#pragma unroll
      for (int f2 = 0; f2 < 4; ++f2) {
        s8v vbh = *(const s8v*)&Vh[f2 * 16 + lr][c * 32 + lk];
        o[f2] = MFMA(pah, vbh, o[f2]);
      }
    }
  }

  // ---- epilogue: /l, write as hi/lo planes [b][s][h*64+d] ----
  const int b = bh >> 4, h = bh & 15;
#pragma unroll
  for (int i = 0; i < 4; ++i) {
    int s = q0 + w * 16 + rg + i;
    float inv = 1.0f / l_run[i];
#pragma unroll
    for (int f2 = 0; f2 < 4; ++f2) {
      int d = f2 * 16 + lr;
      float val = o[f2][i] * inv;
      size_t off = ((size_t)(b * S_LEN + s)) * D_MODEL + h * DH + d;
      u16 hi = f2bf(val);
      ohp[off] = hi;
      olp[off] = f2bf_trunc(val - bf2f(hi));
    }
  }
}

// ---------------------------------------------------------------------------
extern "C" void kernel_launch(void* const* d_in, const int* in_sizes, int n_in,
                              void* d_out, int out_size, void* d_ws, size_t ws_size,
                              hipStream_t stream) {
  const float* x     = (const float*)d_in[0];   // [8192,1024]
  const float* w_qkv = (const float*)d_in[1];   // [3072,1024]
  const float* w_out = (const float*)d_in[2];   // [1024,1024]
  float* out = (float*)d_out;

  const size_t NQ = (size_t)BATCH * NH * S_LEN * DH;   // 8388608 (= M*D_MODEL)
  const size_t NWQ = (size_t)3 * D_MODEL * D_MODEL;    // 3145728
  const size_t NWO = (size_t)D_MODEL * D_MODEL;        // 1048576

  float* ws  = (float*)d_ws;
  float* tab = ws;                          // 131072 f32
  float* vw  = ws + 131072;                 // NQ f32 (v, dead after vtrans)
  u16* u   = (u16*)(vw + NQ);
  u16* xh  = u;  u += NQ;                   // reused as oh after gemm<1>
  u16* xl  = u;  u += NQ;                   // reused as ol
  u16* wqh = u;  u += NWQ;
  u16* wql = u;  u += NWQ;
  u16* woh = u;  u += NWO;
  u16* wol = u;  u += NWO;
  u16* qh  = u;  u += NQ;
  u16* ql  = u;  u += NQ;
  u16* kh  = u;  u += NQ;
  u16* kl  = u;  u += NQ;
  u16* vth = u;  u += NQ;
  // total ~169 MB

  const int M = BATCH * S_LEN;   // 8192

  rope_table_kernel<<<(S_LEN * 32 + 255) / 256, 256, 0, stream>>>(tab);

  split_kernel<<<(int)(NQ / 4 + 255) / 256, 256, 0, stream>>>(x, xh, xl, (int)(NQ / 4));
  split_kernel<<<(int)(NWQ / 4 + 255) / 256, 256, 0, stream>>>(w_qkv, wqh, wql, (int)(NWQ / 4));
  split_kernel<<<(int)(NWO / 4 + 255) / 256, 256, 0, stream>>>(w_out, woh, wol, (int)(NWO / 4));

  gemm2<1><<<dim3(3 * D_MODEL / 128, M / 128), 256, 0, stream>>>(
      xh, xl, wqh, wql, nullptr, qh, ql, kh, kl, vw, tab, M, 3 * D_MODEL, D_MODEL);

  vtrans_kernel<<<dim3(S_LEN / 64, BATCH * NH), 256, 0, stream>>>(vw, vth);

  u16* oh = xh;   // x planes dead after QKV gemm
  u16* ol = xl;
  attn4_kernel<<<dim3(S_LEN / 64 * BATCH * NH), 256, 0, stream>>>(
      qh, ql, kh, kl, vth, oh, ol);

  gemm2<0><<<dim3(D_MODEL / 128, M / 128), 256, 0, stream>>>(
      oh, ol, woh, wol, out, nullptr, nullptr, nullptr, nullptr, nullptr, tab,
      M, D_MODEL, D_MODEL);
}